// Round 5
// baseline (46.239 us; speedup 1.0000x reference)
//
#include <hip/hip_runtime.h>
#include <hip/hip_bf16.h>

#define B_  32
#define N_  128
#define AH_ 512
#define AW_ 512

// compiler-only reordering fence (LDS ops of ONE wave execute in issue order
// in the DS pipe; we only need to stop the compiler moving reads past writes)
#define CFENCE() asm volatile("" ::: "memory")

// ---------------------------------------------------------------------------
// 256 threads = 4 INDEPENDENT waves; each wave owns 2 consecutive rows and a
// private 512-float LDS mask slice. No __syncthreads anywhere (R4 showed
// 64-thread blocks halve occupancy via the ~16 WG/CU cap; R3 showed inter-wave
// lockstep barriers cost; this gets both: full occupancy + independence).
//
// Per wave:
//   - box geometry for boxes {lane, lane+64} computed once into REGISTERS
//   - per row: ballot of row-covering boxes; walk the (wave-uniform) mask
//     with __ffsll, broadcast box params via __shfl (v_readlane) -- no LDS
//     box list, no dependent ds_read chain (R3/R4's bottleneck)
//   - span-rasterize with edges folded into one predicated write:
//         val = (x==x1 ? row*x1m : row) * (x==x2-1 ? x2m : 1)
//   - BCE sweep (float4 global + LDS), per-256px-chunk __any gate skips
//     log(p) where the mask chunk is all zero
// ---------------------------------------------------------------------------
__global__ __launch_bounds__(256) void row_bce_kernel(
    const float* __restrict__ att,
    const float* __restrict__ bboxs,
    const int*   __restrict__ img_h_p,
    const int*   __restrict__ img_w_p,
    float*       __restrict__ wave_sums)
{
    const int t    = threadIdx.x;
    const int lane = t & 63;
    const int wid  = t >> 6;                     // 0..3
    const int b    = blockIdx.x >> 6;            // 64 blocks per image
    const int pair = ((blockIdx.x & 63) << 2) | wid;  // 0..255
    const int y0   = pair << 1;

    __shared__ float s_mask[4][AW_];
    float*  mrow  = s_mask[wid];
    float4* mrow4 = (float4*)mrow;

    const float fw  = (float)(*img_w_p);
    const float fh  = (float)(*img_h_p);
    const float sxs = (float)AW_ / fw;
    const float sys = (float)AH_ / fh;

    // ---- box geometry, once per wave (boxes lane and lane+64), registers ----
    bool  valid[2];
    int   gx1[2], gx2[2], gy1[2], gy2[2];
    float gx1m[2], gx2m[2], gy1m[2], gy2m[2];
    #pragma unroll
    for (int k = 0; k < 2; ++k) {
        const int n = lane + 64 * k;
        const float* bp = bboxs + ((size_t)b * N_ + n) * 5;
        const float c0 = bp[0], c1 = bp[1], c2 = bp[2], c3 = bp[3], lab = bp[4];
        valid[k] = (lab != -1.0f) && (c0 <= fw) && (c1 <= fh)
                                  && (c2 <= fw) && (c3 <= fh);
        const float bx1 = c0 * sxs, by1 = c1 * sys;
        const float bx2 = c2 * sxs, by2 = c3 * sys;
        const float fx1 = floorf(bx1), fy1 = floorf(by1);
        gx1m[k] = fx1 + 1.0f - bx1;
        gy1m[k] = fy1 + 1.0f - by1;
        gx2m[k] = bx2 - floorf(bx2);
        gy2m[k] = by2 - floorf(by2);
        gx1[k] = (int)fmaxf(fx1, 0.0f);
        gy1[k] = (int)fmaxf(fy1, 0.0f);
        gx2[k] = (int)fminf(ceilf(bx2) + 1.0f, (float)AW_);
        gy2[k] = (int)fminf(ceilf(by2) + 1.0f, (float)AH_);
    }

    const float4* p4base = (const float4*)(att + ((size_t)b * AH_ + y0) * AW_);
    float acc = 0.0f;

    for (int r = 0; r < 2; ++r) {
        const int y = y0 + r;

        // per-row coverage + per-box row weight (computed by ALL lanes:
        // readlane below ignores exec, sources must be unconditionally live)
        bool  act[2];
        float rowv[2], lftv[2];
        #pragma unroll
        for (int k = 0; k < 2; ++k) {
            act[k]  = valid[k] && (y >= gy1[k]) && (y < gy2[k]);
            rowv[k] = ((y == gy1[k])     ? gy1m[k] : 1.0f)
                    * ((y == gy2[k] - 1) ? gy2m[k] : 1.0f);
            lftv[k] = rowv[k] * gx1m[k];
        }
        const unsigned long long bal0 = __ballot(act[0]);
        const unsigned long long bal1 = __ballot(act[1]);
        const bool have = (bal0 | bal1) != 0ull;

        if (have) {
            // zero the wave's mask row (2x ds_write_b128 per lane)
            const float4 z = make_float4(0.f, 0.f, 0.f, 0.f);
            mrow4[lane]      = z;
            mrow4[lane + 64] = z;
            CFENCE();
            // walk ballot masks in box-index order (k=0: boxes 0..63 first)
            #pragma unroll
            for (int k = 0; k < 2; ++k) {
                unsigned long long m = (k == 0) ? bal0 : bal1;
                while (m) {
                    const int src = __ffsll(m) - 1;
                    m &= m - 1;
                    const int   e1 = __shfl(gx1[k],  src);
                    const int   e2 = __shfl(gx2[k],  src);
                    const float vi = __shfl(rowv[k], src);
                    const float vl = __shfl(lftv[k], src);
                    const float rm = __shfl(gx2m[k], src);
                    for (int x = e1 + lane; x < e2; x += 64) {
                        const float v = ((x == e1)     ? vl : vi)
                                      * ((x == e2 - 1) ? rm : 1.0f);
                        mrow[x] = v;
                    }
                }
            }
            CFENCE();
        }

        // ---- BCE sweep: 2 chunks of 256 px (float4/lane) ----
        #pragma unroll
        for (int h = 0; h < 2; ++h) {
            const float4 p = p4base[r * 128 + lane + 64 * h];
            float4 mv4 = make_float4(0.f, 0.f, 0.f, 0.f);
            if (have) mv4 = mrow4[lane + 64 * h];
            const float pv[4] = {p.x, p.y, p.z, p.w};
            const float mv[4] = {mv4.x, mv4.y, mv4.z, mv4.w};
            const bool nz = (mv4.x != 0.f) | (mv4.y != 0.f)
                          | (mv4.z != 0.f) | (mv4.w != 0.f);
            if (__any(nz)) {
                #pragma unroll
                for (int j = 0; j < 4; ++j) {
                    const float lp = fmaxf(__logf(pv[j]),        -100.0f);
                    const float l1 = fmaxf(__logf(1.0f - pv[j]), -100.0f);
                    acc += l1 + mv[j] * (lp - l1);
                }
            } else {
                #pragma unroll
                for (int j = 0; j < 4; ++j)
                    acc += fmaxf(__logf(1.0f - pv[j]), -100.0f);
            }
        }
        CFENCE();   // keep next row's mask-init after this row's LDS reads
    }

    // ---- wave reduction -> per-wave partial (no cross-wave traffic) ----
    #pragma unroll
    for (int off = 32; off; off >>= 1) acc += __shfl_down(acc, off, 64);
    if (lane == 0) wave_sums[(blockIdx.x << 2) | wid] = acc;
}

// ---------------------------------------------------------------------------
// Fused tail: per-image reduce of 256 wave partials + any_valid gate +
// batch mean. One block, 1024 threads (32 workers per image).
// ---------------------------------------------------------------------------
__global__ __launch_bounds__(1024) void final_kernel(
    const float* __restrict__ bboxs,
    const int*   __restrict__ img_h_p,
    const int*   __restrict__ img_w_p,
    const float* __restrict__ wave_sums,
    float*       __restrict__ out)
{
    const int t = threadIdx.x;
    const int b = t >> 5;        // image 0..31
    const int j = t & 31;        // worker within image

    __shared__ float s_sum[1024];
    __shared__ int   s_any[1024];
    __shared__ float s_loss[B_];

    float s = 0.0f;
    #pragma unroll
    for (int k = 0; k < 8; ++k) s += wave_sums[b * 256 + j + 32 * k];
    s_sum[t] = s;

    const float fw = (float)(*img_w_p);
    const float fh = (float)(*img_h_p);
    int av = 0;
    const float* bp = bboxs + (size_t)b * N_ * 5;
    #pragma unroll
    for (int n = j * 4; n < j * 4 + 4; ++n) {
        const float c0 = bp[n * 5 + 0];
        const float c1 = bp[n * 5 + 1];
        const float c2 = bp[n * 5 + 2];
        const float c3 = bp[n * 5 + 3];
        const float lab = bp[n * 5 + 4];
        av |= ((lab != -1.0f) && (c0 <= fw) && (c1 <= fh)
                              && (c2 <= fw) && (c3 <= fh)) ? 1 : 0;
    }
    s_any[t] = av;
    __syncthreads();

    if (j == 0) {
        float sum = 0.0f;
        int anyv = 0;
        for (int k = 0; k < 32; ++k) {
            sum  += s_sum[b * 32 + k];
            anyv |= s_any[b * 32 + k];
        }
        s_loss[b] = anyv ? (-sum * (1.0f / (float)(AH_ * AW_))) : 0.0f;
    }
    __syncthreads();

    if (t == 0) {
        float total = 0.0f;
        for (int k = 0; k < B_; ++k) total += s_loss[k];
        out[0] = total * (1.0f / (float)B_);
    }
}

extern "C" void kernel_launch(void* const* d_in, const int* in_sizes, int n_in,
                              void* d_out, int out_size, void* d_ws, size_t ws_size,
                              hipStream_t stream)
{
    const float* att   = (const float*)d_in[0];   // (32,1,512,512) f32
    const float* bboxs = (const float*)d_in[1];   // (32,128,5) f32
    const int*   img_h = (const int*)d_in[2];     // scalar
    const int*   img_w = (const int*)d_in[3];     // scalar
    float* out = (float*)d_out;
    float* wave_sums = (float*)d_ws;              // 8192 floats (32 KB)

    row_bce_kernel<<<B_ * AH_ / 8, 256, 0, stream>>>(att, bboxs, img_h, img_w, wave_sums);
    final_kernel<<<1, 1024, 0, stream>>>(bboxs, img_h, img_w, wave_sums, out);
}

// Round 6
// 29.355 us; speedup vs baseline: 1.5751x; 1.5751x over previous
//
#include <hip/hip_runtime.h>
#include <hip/hip_bf16.h>

#define B_   32
#define N_   128
#define AH_  512
#define AW_  512
#define LCAP 64    // per-chunk list capacity (one 64-box ballot chunk)

// compiler-only reordering fence; one wave's DS ops execute in issue order
#define CFENCE() asm volatile("" ::: "memory")

// ---------------------------------------------------------------------------
// 128 threads = 2 INDEPENDENT waves (no __syncthreads). Each wave owns TWO
// consecutive rows {y0, y0+1} of one image, with private LDS: a 64-entry box
// list (reused across the two 64-box chunks) and a [2][512] mask.
//
// Per wave:
//   - att float4 loads for both rows issued FIRST (latency hides under geom)
//   - box geometry for boxes {lane, lane+64} once into registers
//   - per chunk k (boxes 0..63, then 64..127, preserving index order):
//       ballot(active on row0 OR row1) -> order-preserving compaction of
//       {pack(x1,x2), x1m, x2m, actbits} + {rowv0, rowv1} into the list;
//       raster loop with 1-deep PREFETCH (breaks the ds_read->use chain);
//       each box writes BOTH rows' spans from one edge computation.
//   - BCE over 2 rows (16 px/lane), per-256px-chunk __any gate on log(p);
//     no fmax clamps (p in [1e-4, 1-1e-4] => log in [-9.22, 0], never -100).
// ---------------------------------------------------------------------------
__global__ __launch_bounds__(128) void row_bce_kernel(
    const float* __restrict__ att,
    const float* __restrict__ bboxs,
    const int*   __restrict__ img_h_p,
    const int*   __restrict__ img_w_p,
    float*       __restrict__ wave_sums)
{
    const int t    = threadIdx.x;
    const int lane = t & 63;
    const int wid  = t >> 6;                    // 0..1
    const int task = (blockIdx.x << 1) | wid;   // 0..8191
    const int b    = task >> 8;                 // 256 tasks per image
    const int y0   = (task & 255) << 1;         // rows y0, y0+1

    __shared__ float4 s_geo[2][LCAP];           // {pack(x1,x2), x1m, x2m, act}
    __shared__ float2 s_rv [2][LCAP];           // {rowv(y0), rowv(y0+1)}
    __shared__ float  s_mask[2][2][AW_];        // [wid][row][x]

    const float fw  = (float)(*img_w_p);
    const float fh  = (float)(*img_h_p);
    const float sxs = (float)AW_ / fw;
    const float sys = (float)AH_ / fh;

    // ---- hoisted attention loads (independent of everything below) ----
    const float4* p4 = (const float4*)(att + ((size_t)b * AH_ + y0) * AW_);
    float4 P[2][2];
    #pragma unroll
    for (int r = 0; r < 2; ++r)
        #pragma unroll
        for (int h = 0; h < 2; ++h)
            P[r][h] = p4[r * 128 + h * 64 + lane];

    // ---- box geometry, once per wave (boxes lane and lane+64) ----
    bool  act_any[2];
    int   actb[2];                 // bit r = box covers row y0+r
    int   gx1[2], gx2[2];
    float gx1m[2], gx2m[2];
    float rv0[2], rv1[2];
    #pragma unroll
    for (int k = 0; k < 2; ++k) {
        const int n = lane + 64 * k;
        const float* bp = bboxs + ((size_t)b * N_ + n) * 5;
        const float c0 = bp[0], c1 = bp[1], c2 = bp[2], c3 = bp[3], lab = bp[4];
        const bool valid = (lab != -1.0f) && (c0 <= fw) && (c1 <= fh)
                                          && (c2 <= fw) && (c3 <= fh);
        const float bx1 = c0 * sxs, by1 = c1 * sys;
        const float bx2 = c2 * sxs, by2 = c3 * sys;
        const float fx1 = floorf(bx1), fy1 = floorf(by1);
        const float x1m = fx1 + 1.0f - bx1;
        const float y1m = fy1 + 1.0f - by1;
        const float x2m = bx2 - floorf(bx2);
        const float y2m = by2 - floorf(by2);
        const int x1 = (int)fmaxf(fx1, 0.0f);
        const int y1 = (int)fmaxf(fy1, 0.0f);
        const int x2 = (int)fminf(ceilf(bx2) + 1.0f, (float)AW_);
        const int y2 = (int)fminf(ceilf(by2) + 1.0f, (float)AH_);
        gx1[k] = x1; gx2[k] = x2; gx1m[k] = x1m; gx2m[k] = x2m;
        int ab = 0;
        #pragma unroll
        for (int r = 0; r < 2; ++r) {
            const int y = y0 + r;
            const bool a = valid && (y >= y1) && (y < y2);
            ab |= a ? (1 << r) : 0;
            const float rw = ((y == y1)     ? y1m : 1.0f)
                           * ((y == y2 - 1) ? y2m : 1.0f);
            if (r == 0) rv0[k] = rw; else rv1[k] = rw;
        }
        actb[k]    = ab;
        act_any[k] = (ab != 0);
    }

    const unsigned long long ltm = (1ull << lane) - 1ull;
    const unsigned long long bal[2] = { __ballot(act_any[0]), __ballot(act_any[1]) };
    const bool have = (bal[0] | bal[1]) != 0ull;

    float*  m0    = s_mask[wid][0];
    float*  m1    = s_mask[wid][1];
    float4* mrow4 = (float4*)s_mask[wid];

    if (have) {
        // zero both mask rows: 4x ds_write_b128 per lane
        const float4 z = make_float4(0.f, 0.f, 0.f, 0.f);
        #pragma unroll
        for (int q = 0; q < 4; ++q) mrow4[lane + 64 * q] = z;
        CFENCE();

        // ---- two chunks in box-index order; list buffer reused ----
        #pragma unroll
        for (int k = 0; k < 2; ++k) {
            const int cnt = __popcll(bal[k]);
            if (cnt == 0) continue;
            if (act_any[k]) {
                const int slot = __popcll(bal[k] & ltm);
                s_geo[wid][slot] = make_float4(
                    __int_as_float(gx1[k] | (gx2[k] << 16)),
                    gx1m[k], gx2m[k], __int_as_float(actb[k]));
                s_rv[wid][slot] = make_float2(rv0[k], rv1[k]);
            }
            CFENCE();   // compaction writes precede list reads (in-order DS)

            // raster with 1-deep prefetch
            float4 g_cur = s_geo[wid][0];
            float2 v_cur = s_rv[wid][0];
            for (int i = 0; i < cnt; ++i) {
                const float4 g = g_cur;
                const float2 v = v_cur;
                if (i + 1 < cnt) {
                    g_cur = s_geo[wid][i + 1];
                    v_cur = s_rv[wid][i + 1];
                }
                const int px = __float_as_int(g.x);
                const int e1 = px & 0xffff;
                const int e2 = px >> 16;
                const int ab = __float_as_int(g.w);
                for (int x = e1 + lane; x < e2; x += 64) {
                    const float edge = ((x == e1)     ? g.y : 1.0f)
                                     * ((x == e2 - 1) ? g.z : 1.0f);
                    if (ab & 1) m0[x] = v.x * edge;
                    if (ab & 2) m1[x] = v.y * edge;
                }
            }
            CFENCE();   // this chunk's raster reads precede next compaction
        }
    }

    // ---- BCE over 2 rows (no fmax clamps: p in [1e-4, 1-1e-4]) ----
    float acc = 0.0f;
    #pragma unroll
    for (int r = 0; r < 2; ++r) {
        #pragma unroll
        for (int h = 0; h < 2; ++h) {
            const float4 p = P[r][h];
            float4 m = make_float4(0.f, 0.f, 0.f, 0.f);
            if (have) m = mrow4[r * 128 + h * 64 + lane];
            const float pv[4] = {p.x, p.y, p.z, p.w};
            const float mv[4] = {m.x, m.y, m.z, m.w};
            const bool nz = (m.x != 0.f) | (m.y != 0.f)
                          | (m.z != 0.f) | (m.w != 0.f);
            if (__any(nz)) {
                #pragma unroll
                for (int j = 0; j < 4; ++j) {
                    const float lp = __logf(pv[j]);
                    const float l1 = __logf(1.0f - pv[j]);
                    acc += l1 + mv[j] * (lp - l1);
                }
            } else {
                #pragma unroll
                for (int j = 0; j < 4; ++j)
                    acc += __logf(1.0f - pv[j]);
            }
        }
    }

    // ---- wave reduction -> per-task partial ----
    #pragma unroll
    for (int off = 32; off; off >>= 1) acc += __shfl_down(acc, off, 64);
    if (lane == 0) wave_sums[task] = acc;
}

// ---------------------------------------------------------------------------
// Fused tail: per-image reduce of 256 task partials + any_valid gate +
// batch mean. One block, 1024 threads (32 workers per image).
// ---------------------------------------------------------------------------
__global__ __launch_bounds__(1024) void final_kernel(
    const float* __restrict__ bboxs,
    const int*   __restrict__ img_h_p,
    const int*   __restrict__ img_w_p,
    const float* __restrict__ wave_sums,
    float*       __restrict__ out)
{
    const int t = threadIdx.x;
    const int b = t >> 5;        // image 0..31
    const int j = t & 31;        // worker within image

    __shared__ float s_sum[1024];
    __shared__ int   s_any[1024];
    __shared__ float s_loss[B_];

    float s = 0.0f;
    #pragma unroll
    for (int k = 0; k < 8; ++k) s += wave_sums[b * 256 + j + 32 * k];
    s_sum[t] = s;

    const float fw = (float)(*img_w_p);
    const float fh = (float)(*img_h_p);
    int av = 0;
    const float* bp = bboxs + (size_t)b * N_ * 5;
    #pragma unroll
    for (int n = j * 4; n < j * 4 + 4; ++n) {
        const float c0 = bp[n * 5 + 0];
        const float c1 = bp[n * 5 + 1];
        const float c2 = bp[n * 5 + 2];
        const float c3 = bp[n * 5 + 3];
        const float lab = bp[n * 5 + 4];
        av |= ((lab != -1.0f) && (c0 <= fw) && (c1 <= fh)
                              && (c2 <= fw) && (c3 <= fh)) ? 1 : 0;
    }
    s_any[t] = av;
    __syncthreads();

    if (j == 0) {
        float sum = 0.0f;
        int anyv = 0;
        for (int k = 0; k < 32; ++k) {
            sum  += s_sum[b * 32 + k];
            anyv |= s_any[b * 32 + k];
        }
        s_loss[b] = anyv ? (-sum * (1.0f / (float)(AH_ * AW_))) : 0.0f;
    }
    __syncthreads();

    if (t == 0) {
        float total = 0.0f;
        for (int k = 0; k < B_; ++k) total += s_loss[k];
        out[0] = total * (1.0f / (float)B_);
    }
}

extern "C" void kernel_launch(void* const* d_in, const int* in_sizes, int n_in,
                              void* d_out, int out_size, void* d_ws, size_t ws_size,
                              hipStream_t stream)
{
    const float* att   = (const float*)d_in[0];   // (32,1,512,512) f32
    const float* bboxs = (const float*)d_in[1];   // (32,128,5) f32
    const int*   img_h = (const int*)d_in[2];     // scalar
    const int*   img_w = (const int*)d_in[3];     // scalar
    float* out = (float*)d_out;
    float* wave_sums = (float*)d_ws;              // 8192 floats (32 KB)

    row_bce_kernel<<<B_ * AH_ / 4, 128, 0, stream>>>(att, bboxs, img_h, img_w, wave_sums);
    final_kernel<<<1, 1024, 0, stream>>>(bboxs, img_h, img_w, wave_sums, out);
}